// Round 13
// baseline (530.513 us; speedup 1.0000x reference)
//
#include <hip/hip_runtime.h>

#define H 128
#define L 256
#define SB 8       // sequences per block
#define NBLK 256   // 2048/SB -> one block per CU
#define NTHR 512   // 8 waves; wave w owns gate-cols 16w..16w+15 of each gate tile

typedef _Float16 f16x8 __attribute__((ext_vector_type(8)));
typedef float f32x4 __attribute__((ext_vector_type(4)));

#define MFMA(accv, av, bv) accv = __builtin_amdgcn_mfma_f32_16x16x32_f16(av, bv, accv, 0, 0, 0)

__device__ __forceinline__ float fsig(float x) {
  return __builtin_amdgcn_rcpf(1.f + __builtin_amdgcn_exp2f(-1.44269504089f * x));
}
__device__ __forceinline__ float ftanh(float x) {
  return 2.f * __builtin_amdgcn_rcpf(1.f + __builtin_amdgcn_exp2f(-2.88539008178f * x)) - 1.f;
}

// Skewed pipeline: phase t computes h1(t) = L0(x(t), h1(t-1)) and
// h2(t-1) = L1(h1(t-1), h2(t-2)); one barrier per phase, 257 phases.
// R7: break the MFMA/VALU convoy (R6: pipes serialized, 39%+48% busy but
// phase = MFMA + VALU + latency). Order: acc1 MFMAs first (L1b with 2-slice
// dbuf Whh1 register prefetch, pinned by sched_barrier(0)), then L1-act
// interleaved with L0's 16 MFMAs via sched_group_barrier, then L0-act.
// Branchless body (zm mask / x clamp) keeps one scheduling region.
// Seq->MFMA-row map: seq s at row 4*(s>>1)+(s&1); each lane owns 2 valid rows.
// LDS f16 tiles swizzled: (row,k) -> row*128 + (k^((row&7)<<3)).

__global__ __launch_bounds__(NTHR, 2) void lstm_kernel(
    const float* __restrict__ xg,
    const float* __restrict__ Wih0, const float* __restrict__ Whh0,
    const float* __restrict__ bih0, const float* __restrict__ bhh0,
    const float* __restrict__ Wih1, const float* __restrict__ Whh1,
    const float* __restrict__ bih1, const float* __restrict__ bhh1,
    const float* __restrict__ W1,   const float* __restrict__ b1v,
    const float* __restrict__ W2,   const float* __restrict__ b2v,
    const float* __restrict__ abias,
    float* __restrict__ out_scores)
{
  __shared__ __align__(16) _Float16 Whh1_s[512 * H];   // 128 KB, row-swizzled
  __shared__ __align__(16) float    x_s[L * SB];       // 8 KB, [t][s]
  __shared__ __align__(16) _Float16 h1_s[2][16 * H];   // 8 KB, double-buffered
  __shared__ __align__(16) _Float16 h2_s[2][16 * H];   // 8 KB

  const int tid  = threadIdx.x;
  const int lane = tid & 63;
  const int w    = tid >> 6;
  const int l15  = lane & 15;
  const int lhi  = lane >> 4;
  const int sb   = blockIdx.x * SB;

  // ---- stage x transposed [t][s] ----
  for (int i = tid; i < SB * L; i += NTHR) {
    int s = i >> 8, t = i & 255;
    x_s[t * SB + s] = xg[(sb + s) * L + t];
  }
  // ---- stage W_hh1 as f16, swizzled ----
  for (int i = tid; i < 512 * H; i += NTHR) {
    int r = i >> 7, k = i & 127;
    Whh1_s[(r << 7) + (k ^ ((r & 7) << 3))] = (_Float16)Whh1[i];
  }
  // ---- zero h state, both buffers ----
  for (int i = tid; i < 16 * H; i += NTHR) {
    h1_s[0][i] = (_Float16)0.f; h1_s[1][i] = (_Float16)0.f;
    h2_s[0][i] = (_Float16)0.f; h2_s[1][i] = (_Float16)0.f;
  }

  // ---- per-wave register weight B-fragments (Whh0, Wih1) ----
  f16x8 whh0f[4][4], wih1f[4][4];
  float b0r[4], b1r[4], w0r[4];
  #pragma unroll
  for (int n = 0; n < 4; ++n) {
    const int c = (n << 7) + (w << 4) + l15;
    b0r[n] = bih0[c] + bhh0[c];
    b1r[n] = bih1[c] + bhh1[c];
    w0r[n] = Wih0[c];
    #pragma unroll
    for (int kk = 0; kk < 4; ++kk) {
      const float* p0 = Whh0 + c * H + (kk << 5) + (lhi << 3);
      const float* p1 = Wih1 + c * H + (kk << 5) + (lhi << 3);
      f16x8 f0, f1;
      #pragma unroll
      for (int j = 0; j < 8; ++j) { f0[j] = (_Float16)p0[j]; f1[j] = (_Float16)p1[j]; }
      whh0f[n][kk] = f0; wih1f[n][kk] = f1;
    }
  }

  float c1[2] = {0.f, 0.f}, c2[2] = {0.f, 0.f};
  const int colh  = (w << 4) | l15;
  const int rown0 = lhi << 2;           // owned rows: rown0, rown0+1
  const int so0   = lhi << 1;           // owned seqs: so0, so0+1
  const int arow  = l15 << 7;           // A-frag row base
  const int aswz  = (l15 & 7) << 3;     // swizzle for row l15 / Whh1 row
  int wrow[4];
  #pragma unroll
  for (int n = 0; n < 4; ++n) wrow[n] = ((n << 7) + colh) << 7;

  __syncthreads();

  #pragma unroll 1
  for (int t = 0; t <= L; ++t) {
    const int pw = t & 1;        // h1 write buf; h2 READ buf (holds h2(t-2))
    const int pr = pw ^ 1;       // h1 read buf (h1(t-1)); h2 write buf (h2(t-1))
    const int tx = (t < L) ? t : (L - 1);       // x clamp (t==L result unused)
    const float zm = (t > 0) ? 1.f : 0.f;       // kill bogus L1 step at t==0

    // ---- load block: a-frags + Whh1 slice 0 + x; pinned by sched_barrier ----
    f16x8 a1f[4], a2f[4], wt0[4], wt1[4];
    #pragma unroll
    for (int kk = 0; kk < 4; ++kk) {
      const int kb = (kk << 5) + (lhi << 3);
      a1f[kk] = *(const f16x8*)&h1_s[pr][arow + (kb ^ aswz)];
      a2f[kk] = *(const f16x8*)&h2_s[pw][arow + (kb ^ aswz)];
    }
    {
      const int kb = (lhi << 3);
      #pragma unroll
      for (int n = 0; n < 4; ++n)
        wt0[n] = *(const f16x8*)&Whh1_s[wrow[n] + (kb ^ aswz)];
    }
    const float2 xv = *(const float2*)&x_s[tx * SB + so0];

    // acc init with bias (and x term for L0) folded in; rows 2,3 unused
    f32x4 acc0[4], acc1[4];
    #pragma unroll
    for (int n = 0; n < 4; ++n) {
      acc0[n][0] = xv.x * w0r[n] + b0r[n];
      acc0[n][1] = xv.y * w0r[n] + b0r[n];
      acc0[n][2] = 0.f; acc0[n][3] = 0.f;
      acc1[n][0] = b1r[n]; acc1[n][1] = b1r[n];
      acc1[n][2] = 0.f; acc1[n][3] = 0.f;
    }
    __builtin_amdgcn_sched_barrier(0);   // keep loads issued up front

    // ---- L1a: 16 reg-fed MFMAs (cover wt-slice LDS latency) ----
    #pragma unroll
    for (int kk = 0; kk < 4; ++kk) {
      MFMA(acc1[0], a1f[kk], wih1f[0][kk]);
      MFMA(acc1[1], a1f[kk], wih1f[1][kk]);
      MFMA(acc1[2], a1f[kk], wih1f[2][kk]);
      MFMA(acc1[3], a1f[kk], wih1f[3][kk]);
    }
    // ---- L1b: 16 MFMAs, 2-slice double-buffered Whh1 prefetch ----
    #pragma unroll
    for (int kk = 0; kk < 4; ++kk) {
      if (kk < 3) {
        const int kb = ((kk + 1) << 5) + (lhi << 3);
        if ((kk & 1) == 0) {
          #pragma unroll
          for (int n = 0; n < 4; ++n)
            wt1[n] = *(const f16x8*)&Whh1_s[wrow[n] + (kb ^ aswz)];
        } else {
          #pragma unroll
          for (int n = 0; n < 4; ++n)
            wt0[n] = *(const f16x8*)&Whh1_s[wrow[n] + (kb ^ aswz)];
        }
      }
      if ((kk & 1) == 0) {
        MFMA(acc1[0], a2f[kk], wt0[0]);
        MFMA(acc1[1], a2f[kk], wt0[1]);
        MFMA(acc1[2], a2f[kk], wt0[2]);
        MFMA(acc1[3], a2f[kk], wt0[3]);
      } else {
        MFMA(acc1[0], a2f[kk], wt1[0]);
        MFMA(acc1[1], a2f[kk], wt1[1]);
        MFMA(acc1[2], a2f[kk], wt1[2]);
        MFMA(acc1[3], a2f[kk], wt1[3]);
      }
    }

    // ---- L1 activation (interleaves with L0 MFMAs below via SGB) ----
    float h2n[2];
    #pragma unroll
    for (int r = 0; r < 2; ++r) {
      float ig = fsig (acc1[0][r]);
      float fg = fsig (acc1[1][r]);
      float gg = ftanh(acc1[2][r]);
      float og = fsig (acc1[3][r]);
      float cn = zm * (fg * c2[r] + ig * gg);
      c2[r] = cn;
      h2n[r] = og * ftanh(cn);     // == 0 at t==0 since cn==0
    }

    // ---- L0: 16 reg-fed MFMAs ----
    #pragma unroll
    for (int kk = 0; kk < 4; ++kk) {
      MFMA(acc0[0], a1f[kk], whh0f[0][kk]);
      MFMA(acc0[1], a1f[kk], whh0f[1][kk]);
      MFMA(acc0[2], a1f[kk], whh0f[2][kk]);
      MFMA(acc0[3], a1f[kk], whh0f[3][kk]);
    }
    // ---- L0 activation ----
    float h1n[2];
    #pragma unroll
    for (int r = 0; r < 2; ++r) {
      float ig = fsig (acc0[0][r]);
      float fg = fsig (acc0[1][r]);
      float gg = ftanh(acc0[2][r]);
      float og = fsig (acc0[3][r]);
      float cc = fg * c1[r] + ig * gg;
      c1[r] = cc;
      h1n[r] = og * ftanh(cc);
    }

    // ---- publish ----
    #pragma unroll
    for (int r = 0; r < 2; ++r) {
      const int row = rown0 + r;
      h1_s[pw][(row << 7) + (colh ^ ((row & 7) << 3))] = (_Float16)h1n[r];
      h2_s[pr][(row << 7) + (colh ^ ((row & 7) << 3))] = (_Float16)h2n[r];
    }

    // ---- scheduler directive sequence (T19): acc1 cluster, then
    //      {2 MFMA | 7 VALU} interleave (acc0 || L1-act), then L0-act, writes
    __builtin_amdgcn_sched_group_barrier(0x008, 32, 0);   // acc1 MFMAs
    #pragma unroll
    for (int i = 0; i < 8; ++i) {
      __builtin_amdgcn_sched_group_barrier(0x008, 2, 0);  // acc0 MFMAs
      __builtin_amdgcn_sched_group_barrier(0x002, 7, 0);  // L1-act VALU
    }
    __builtin_amdgcn_sched_group_barrier(0x002, 56, 0);   // L0-act VALU
    __builtin_amdgcn_sched_group_barrier(0x200, 4, 0);    // h writes
    __syncthreads();
  }

  // ================= MLP head =================
  // final h2 = h2(L-1), in h2_s[1] (written at phase t==L, pr==1)
  float* W1t = (float*)Whh1_s;          // [k][j] transposed fp32, 64 KB
  for (int i = tid; i < H * H; i += NTHR) {
    int j = i >> 7, k = i & 127;
    W1t[(k << 7) + j] = W1[i];
  }
  __syncthreads();
  {
    const int s   = w;                           // wave w <-> seq w
    const int row = ((s >> 1) << 2) | (s & 1);   // seq->row map
    float a0 = 0.f, a1 = 0.f;
    for (int k = 0; k < H; ++k) {
      float hv = (float)h2_s[1][(row << 7) + (k ^ ((row & 7) << 3))];  // broadcast
      a0 += hv * W1t[(k << 7) + lane];
      a1 += hv * W1t[(k << 7) + lane + 64];
    }
    a0 = fmaxf(a0 + b1v[lane], 0.f);
    a1 = fmaxf(a1 + b1v[lane + 64], 0.f);
    float part = a0 * W2[lane] + a1 * W2[lane + 64];
    #pragma unroll
    for (int off = 32; off >= 1; off >>= 1) part += __shfl_xor(part, off, 64);
    if (lane == 0)
      out_scores[sb + s] = part + b2v[0] + abias[(sb + s) & 63];
  }
}

// softmax over each row of 64 (one wave per row), in-place on d_out
__global__ void softmax_kernel(float* __restrict__ out) {
  const int b = blockIdx.x, n = threadIdx.x;
  float v = out[(b << 6) + n];
  float m = v;
  #pragma unroll
  for (int off = 32; off >= 1; off >>= 1) m = fmaxf(m, __shfl_xor(m, off, 64));
  float e = __builtin_amdgcn_exp2f((v - m) * 1.44269504089f);
  float s = e;
  #pragma unroll
  for (int off = 32; off >= 1; off >>= 1) s += __shfl_xor(s, off, 64);
  out[(b << 6) + n] = e / s;
}

extern "C" void kernel_launch(void* const* d_in, const int* in_sizes, int n_in,
                              void* d_out, int out_size, void* d_ws, size_t ws_size,
                              hipStream_t stream) {
  (void)in_sizes; (void)n_in; (void)d_ws; (void)ws_size; (void)out_size;
  const float* xg   = (const float*)d_in[0];
  const float* Wih0 = (const float*)d_in[1];
  const float* Whh0 = (const float*)d_in[2];
  const float* bih0 = (const float*)d_in[3];
  const float* bhh0 = (const float*)d_in[4];
  const float* Wih1 = (const float*)d_in[5];
  const float* Whh1 = (const float*)d_in[6];
  const float* bih1 = (const float*)d_in[7];
  const float* bhh1 = (const float*)d_in[8];
  const float* W1   = (const float*)d_in[9];
  const float* b1   = (const float*)d_in[10];
  const float* W2   = (const float*)d_in[11];
  const float* b2   = (const float*)d_in[12];
  const float* ab   = (const float*)d_in[13];
  float* out = (float*)d_out;

  lstm_kernel<<<NBLK, NTHR, 0, stream>>>(xg, Wih0, Whh0, bih0, bhh0,
                                         Wih1, Whh1, bih1, bhh1,
                                         W1, b1, W2, b2, ab, out);
  softmax_kernel<<<32, 64, 0, stream>>>(out);
}

// Round 14
// 449.005 us; speedup vs baseline: 1.1815x; 1.1815x over previous
//
#include <hip/hip_runtime.h>

#define H 128
#define L 256
#define SB 8       // sequences per block
#define NBLK 256   // 2048/SB -> one block per CU
#define NTHR 512   // 8 waves; wave w owns gate-cols 16w..16w+15 of each gate tile

typedef _Float16 f16x8 __attribute__((ext_vector_type(8)));
typedef float f32x4 __attribute__((ext_vector_type(4)));

#define MFMA(accv, av, bv) accv = __builtin_amdgcn_mfma_f32_16x16x32_f16(av, bv, accv, 0, 0, 0)

__device__ __forceinline__ float fsig(float x) {
  return __builtin_amdgcn_rcpf(1.f + __builtin_amdgcn_exp2f(-1.44269504089f * x));
}
__device__ __forceinline__ float ftanh(float x) {
  return 2.f * __builtin_amdgcn_rcpf(1.f + __builtin_amdgcn_exp2f(-2.88539008178f * x)) - 1.f;
}

// Skewed pipeline: phase t computes h1(t) = L0(x(t), h1(t-1)) and
// h2(t-1) = L1(h1(t-1), h2(t-2)); one barrier per phase, 257 phases.
// R14: dual-pipe overlap WITHOUT fences (R13: SGB+pinned loads -> 2.5MB spill
// traffic, dur 463->517; lesson = m141/T19: order-pinning freezes live ranges).
// Instead: per-gate dataflow stagger in plain source order. acc1 gates first
// (L1a reg-fed, L1b streamed per-gate from LDS like R6); gate-n act placed
// after gate-n+1's MFMA batch so act VALU issues while MFMAs crunch in the
// background (in-order wave, independent insts). Then acc0 per-gate with L0
// acts staggered the same way. Branchless body (zm / x-clamp), no wt arrays.
// Seq->MFMA-row map: seq s at row 4*(s>>1)+(s&1); each lane owns 2 valid rows.
// LDS f16 tiles swizzled: (row,k) -> row*128 + (k^((row&7)<<3)).

__global__ __launch_bounds__(NTHR, 2) void lstm_kernel(
    const float* __restrict__ xg,
    const float* __restrict__ Wih0, const float* __restrict__ Whh0,
    const float* __restrict__ bih0, const float* __restrict__ bhh0,
    const float* __restrict__ Wih1, const float* __restrict__ Whh1,
    const float* __restrict__ bih1, const float* __restrict__ bhh1,
    const float* __restrict__ W1,   const float* __restrict__ b1v,
    const float* __restrict__ W2,   const float* __restrict__ b2v,
    const float* __restrict__ abias,
    float* __restrict__ out_scores)
{
  __shared__ __align__(16) _Float16 Whh1_s[512 * H];   // 128 KB, row-swizzled
  __shared__ __align__(16) float    x_s[L * SB];       // 8 KB, [t][s]
  __shared__ __align__(16) _Float16 h1_s[2][16 * H];   // 8 KB, double-buffered
  __shared__ __align__(16) _Float16 h2_s[2][16 * H];   // 8 KB

  const int tid  = threadIdx.x;
  const int lane = tid & 63;
  const int w    = tid >> 6;
  const int l15  = lane & 15;
  const int lhi  = lane >> 4;
  const int sb   = blockIdx.x * SB;

  // ---- stage x transposed [t][s] ----
  for (int i = tid; i < SB * L; i += NTHR) {
    int s = i >> 8, t = i & 255;
    x_s[t * SB + s] = xg[(sb + s) * L + t];
  }
  // ---- stage W_hh1 as f16, swizzled ----
  for (int i = tid; i < 512 * H; i += NTHR) {
    int r = i >> 7, k = i & 127;
    Whh1_s[(r << 7) + (k ^ ((r & 7) << 3))] = (_Float16)Whh1[i];
  }
  // ---- zero h state, both buffers ----
  for (int i = tid; i < 16 * H; i += NTHR) {
    h1_s[0][i] = (_Float16)0.f; h1_s[1][i] = (_Float16)0.f;
    h2_s[0][i] = (_Float16)0.f; h2_s[1][i] = (_Float16)0.f;
  }

  // ---- per-wave register weight B-fragments (Whh0, Wih1) ----
  f16x8 whh0f[4][4], wih1f[4][4];
  float b0r[4], b1r[4], w0r[4];
  #pragma unroll
  for (int n = 0; n < 4; ++n) {
    const int c = (n << 7) + (w << 4) + l15;
    b0r[n] = bih0[c] + bhh0[c];
    b1r[n] = bih1[c] + bhh1[c];
    w0r[n] = Wih0[c];
    #pragma unroll
    for (int kk = 0; kk < 4; ++kk) {
      const float* p0 = Whh0 + c * H + (kk << 5) + (lhi << 3);
      const float* p1 = Wih1 + c * H + (kk << 5) + (lhi << 3);
      f16x8 f0, f1;
      #pragma unroll
      for (int j = 0; j < 8; ++j) { f0[j] = (_Float16)p0[j]; f1[j] = (_Float16)p1[j]; }
      whh0f[n][kk] = f0; wih1f[n][kk] = f1;
    }
  }

  float c1[2] = {0.f, 0.f}, c2[2] = {0.f, 0.f};
  const int colh  = (w << 4) | l15;
  const int rown0 = lhi << 2;           // owned rows: rown0, rown0+1
  const int so0   = lhi << 1;           // owned seqs: so0, so0+1
  const int arow  = l15 << 7;           // A-frag row base
  const int aswz  = (l15 & 7) << 3;     // swizzle for row l15 / Whh1 row
  int wrow[4];
  #pragma unroll
  for (int n = 0; n < 4; ++n) wrow[n] = ((n << 7) + colh) << 7;

  __syncthreads();

  #pragma unroll 1
  for (int t = 0; t <= L; ++t) {
    const int pw = t & 1;        // h1 write buf; h2 READ buf (holds h2(t-2))
    const int pr = pw ^ 1;       // h1 read buf (h1(t-1)); h2 write buf (h2(t-1))
    const int tx = (t < L) ? t : (L - 1);       // x clamp (t==L result unused)
    const float zm = (t > 0) ? 1.f : 0.f;       // kill bogus L1 step at t==0

    // ---- a-frags: h1(t-1), h2(t-2) (both published by last barrier) ----
    f16x8 a1f[4], a2f[4];
    #pragma unroll
    for (int kk = 0; kk < 4; ++kk) {
      const int kb = (kk << 5) + (lhi << 3);
      a1f[kk] = *(const f16x8*)&h1_s[pr][arow + (kb ^ aswz)];
      a2f[kk] = *(const f16x8*)&h2_s[pw][arow + (kb ^ aswz)];
    }
    const float2 xv = *(const float2*)&x_s[tx * SB + so0];

    // ================= L1 (acc1): gates i,f,g,o =================
    f32x4 acc1[4];
    #pragma unroll
    for (int n = 0; n < 4; ++n) {
      acc1[n][0] = b1r[n]; acc1[n][1] = b1r[n];
      acc1[n][2] = 0.f;    acc1[n][3] = 0.f;
    }
    // L1a: 16 reg-fed MFMAs (Wih1 · h1(t-1))
    #pragma unroll
    for (int kk = 0; kk < 4; ++kk) {
      MFMA(acc1[0], a1f[kk], wih1f[0][kk]);
      MFMA(acc1[1], a1f[kk], wih1f[1][kk]);
      MFMA(acc1[2], a1f[kk], wih1f[2][kk]);
      MFMA(acc1[3], a1f[kk], wih1f[3][kk]);
    }
    // L1b per-gate (Whh1 · h2(t-2), B streamed from LDS), acts staggered:
    // gate-n act issues while gate-n+1's MFMAs run in the MFMA pipe.
    #pragma unroll
    for (int kk = 0; kk < 4; ++kk)
      MFMA(acc1[0], a2f[kk], *(const f16x8*)&Whh1_s[wrow[0] + (((kk << 5) + (lhi << 3)) ^ aswz)]);
    #pragma unroll
    for (int kk = 0; kk < 4; ++kk)
      MFMA(acc1[1], a2f[kk], *(const f16x8*)&Whh1_s[wrow[1] + (((kk << 5) + (lhi << 3)) ^ aswz)]);
    float i1[2];
    i1[0] = fsig(acc1[0][0]); i1[1] = fsig(acc1[0][1]);      // || gate-2 MFMAs
    #pragma unroll
    for (int kk = 0; kk < 4; ++kk)
      MFMA(acc1[2], a2f[kk], *(const f16x8*)&Whh1_s[wrow[2] + (((kk << 5) + (lhi << 3)) ^ aswz)]);
    float f1g[2];
    f1g[0] = fsig(acc1[1][0]); f1g[1] = fsig(acc1[1][1]);    // || gate-3 MFMAs
    #pragma unroll
    for (int kk = 0; kk < 4; ++kk)
      MFMA(acc1[3], a2f[kk], *(const f16x8*)&Whh1_s[wrow[3] + (((kk << 5) + (lhi << 3)) ^ aswz)]);
    float g1g[2];
    g1g[0] = ftanh(acc1[2][0]); g1g[1] = ftanh(acc1[2][1]);
    float h2n[2];
    #pragma unroll
    for (int r = 0; r < 2; ++r) {
      float og = fsig(acc1[3][r]);
      float cn = zm * (f1g[r] * c2[r] + i1[r] * g1g[r]);
      c2[r] = cn;
      h2n[r] = og * ftanh(cn);     // == 0 at t==0 since cn==0
    }
    #pragma unroll
    for (int r = 0; r < 2; ++r) {
      const int row = rown0 + r;
      h2_s[pr][(row << 7) + (colh ^ ((row & 7) << 3))] = (_Float16)h2n[r];
    }

    // ================= L0 (acc0): gates i,f,g,o =================
    f32x4 acc0[4];
    #pragma unroll
    for (int n = 0; n < 4; ++n) {
      acc0[n][0] = xv.x * w0r[n] + b0r[n];
      acc0[n][1] = xv.y * w0r[n] + b0r[n];
      acc0[n][2] = 0.f; acc0[n][3] = 0.f;
    }
    #pragma unroll
    for (int kk = 0; kk < 4; ++kk) MFMA(acc0[0], a1f[kk], whh0f[0][kk]);
    #pragma unroll
    for (int kk = 0; kk < 4; ++kk) MFMA(acc0[1], a1f[kk], whh0f[1][kk]);
    float i0[2];
    i0[0] = fsig(acc0[0][0]); i0[1] = fsig(acc0[0][1]);      // || gate-2 MFMAs
    #pragma unroll
    for (int kk = 0; kk < 4; ++kk) MFMA(acc0[2], a1f[kk], whh0f[2][kk]);
    float f0g[2];
    f0g[0] = fsig(acc0[1][0]); f0g[1] = fsig(acc0[1][1]);    // || gate-3 MFMAs
    #pragma unroll
    for (int kk = 0; kk < 4; ++kk) MFMA(acc0[3], a1f[kk], whh0f[3][kk]);
    float g0g[2];
    g0g[0] = ftanh(acc0[2][0]); g0g[1] = ftanh(acc0[2][1]);
    float h1n[2];
    #pragma unroll
    for (int r = 0; r < 2; ++r) {
      float og = fsig(acc0[3][r]);
      float cc = f0g[r] * c1[r] + i0[r] * g0g[r];
      c1[r] = cc;
      h1n[r] = og * ftanh(cc);
    }
    #pragma unroll
    for (int r = 0; r < 2; ++r) {
      const int row = rown0 + r;
      h1_s[pw][(row << 7) + (colh ^ ((row & 7) << 3))] = (_Float16)h1n[r];
    }

    __syncthreads();   // publish h1(t), h2(t-1); orders buffer reuse
  }

  // ================= MLP head =================
  // final h2 = h2(L-1), in h2_s[1] (written at phase t==L, pr==1)
  float* W1t = (float*)Whh1_s;          // [k][j] transposed fp32, 64 KB
  for (int i = tid; i < H * H; i += NTHR) {
    int j = i >> 7, k = i & 127;
    W1t[(k << 7) + j] = W1[i];
  }
  __syncthreads();
  {
    const int s   = w;                           // wave w <-> seq w
    const int row = ((s >> 1) << 2) | (s & 1);   // seq->row map
    float a0 = 0.f, a1 = 0.f;
    for (int k = 0; k < H; ++k) {
      float hv = (float)h2_s[1][(row << 7) + (k ^ ((row & 7) << 3))];  // broadcast
      a0 += hv * W1t[(k << 7) + lane];
      a1 += hv * W1t[(k << 7) + lane + 64];
    }
    a0 = fmaxf(a0 + b1v[lane], 0.f);
    a1 = fmaxf(a1 + b1v[lane + 64], 0.f);
    float part = a0 * W2[lane] + a1 * W2[lane + 64];
    #pragma unroll
    for (int off = 32; off >= 1; off >>= 1) part += __shfl_xor(part, off, 64);
    if (lane == 0)
      out_scores[sb + s] = part + b2v[0] + abias[(sb + s) & 63];
  }
}

// softmax over each row of 64 (one wave per row), in-place on d_out
__global__ void softmax_kernel(float* __restrict__ out) {
  const int b = blockIdx.x, n = threadIdx.x;
  float v = out[(b << 6) + n];
  float m = v;
  #pragma unroll
  for (int off = 32; off >= 1; off >>= 1) m = fmaxf(m, __shfl_xor(m, off, 64));
  float e = __builtin_amdgcn_exp2f((v - m) * 1.44269504089f);
  float s = e;
  #pragma unroll
  for (int off = 32; off >= 1; off >>= 1) s += __shfl_xor(s, off, 64);
  out[(b << 6) + n] = e / s;
}

extern "C" void kernel_launch(void* const* d_in, const int* in_sizes, int n_in,
                              void* d_out, int out_size, void* d_ws, size_t ws_size,
                              hipStream_t stream) {
  (void)in_sizes; (void)n_in; (void)d_ws; (void)ws_size; (void)out_size;
  const float* xg   = (const float*)d_in[0];
  const float* Wih0 = (const float*)d_in[1];
  const float* Whh0 = (const float*)d_in[2];
  const float* bih0 = (const float*)d_in[3];
  const float* bhh0 = (const float*)d_in[4];
  const float* Wih1 = (const float*)d_in[5];
  const float* Whh1 = (const float*)d_in[6];
  const float* bih1 = (const float*)d_in[7];
  const float* bhh1 = (const float*)d_in[8];
  const float* W1   = (const float*)d_in[9];
  const float* b1   = (const float*)d_in[10];
  const float* W2   = (const float*)d_in[11];
  const float* b2   = (const float*)d_in[12];
  const float* ab   = (const float*)d_in[13];
  float* out = (float*)d_out;

  lstm_kernel<<<NBLK, NTHR, 0, stream>>>(xg, Wih0, Whh0, bih0, bhh0,
                                         Wih1, Whh1, bih1, bhh1,
                                         W1, b1, W2, b2, ab, out);
  softmax_kernel<<<32, 64, 0, stream>>>(out);
}